// Round 7
// baseline (864.768 us; speedup 1.0000x reference)
//
#include <hip/hip_runtime.h>
#include <math.h>

#define NG 1024
#define NC 2
#define HH 224
#define WW 224
#define EPS2D 0.3f
#define ALPHA_MIN (1.0f/255.0f)
#define ALPHA_MAX 0.999f
#define NBLOCKS 784

// Workspace layout (float units):
//   z    at Z_OFF : NC*NG
//   B    at B_OFF : NC*NG*12 depth-sorted AoS (u,v,ia,ib | id,o,r,g | b,0,0,0)
//   bbox at BB_OFF: NC*NG packed uints (tile tx0|tx1<<8|ty0<<16|ty1<<24), sorted order
//   cnt  at CNT_OFF: 2 uints — DIY grid-barrier arrival counters (memset to 0 pre-launch)
#define Z_OFF   0
#define B_OFF   (NC*NG)
#define BB_OFF  (B_OFF + NC*NG*12)
#define CNT_OFF (BB_OFF + NC*NG)

// Device-scope arrival barrier. Safe because grid (784) <= co-resident
// capacity (4 blocks/CU * 256 CU = 1024 at __launch_bounds__(256,4)).
// Agent-scope acq_rel/acquire makes phase writes visible across XCDs
// (scoped atomics emit the L2 wb/inv the gfx950 memory model requires);
// every block does its own acquire, so every XCD gets invalidated.
__device__ __forceinline__ void grid_barrier(unsigned int* cnt, unsigned int target) {
    __syncthreads();
    if (threadIdx.x == 0) {
        __hip_atomic_fetch_add(cnt, 1u, __ATOMIC_ACQ_REL, __HIP_MEMORY_SCOPE_AGENT);
        while (__hip_atomic_load(cnt, __ATOMIC_ACQUIRE, __HIP_MEMORY_SCOPE_AGENT) < target) {
            __builtin_amdgcn_s_sleep(2);
        }
    }
    __syncthreads();
}

// Single dispatch: phase 1 (blocks 0-7) prep -> barrier -> phase 2 (blocks
// 0-7) rank+scatter (record held in REGISTERS across the barrier; rank
// compares the STORED z array so the permutation is exact) -> barrier ->
// phase 3 (all 784 blocks) render, looping both cameras.
__global__ __launch_bounds__(256, 4) void fused_kernel(
        const float* __restrict__ w2cs, const float* __restrict__ Ks,
        const float* __restrict__ xyz, const float* __restrict__ rgb,
        const float* __restrict__ opac, const float* __restrict__ scale,
        const float* __restrict__ rot, float* __restrict__ out,
        float* __restrict__ ws) {
    const int b   = blockIdx.y * 28 + blockIdx.x;
    const int tid = threadIdx.x;
    unsigned int* cnt = (unsigned int*)(ws + CNT_OFF);

    // per-thread record, persisted phase 1 -> phase 2
    float u=0.f, v=0.f, ia=0.f, ib=0.f, id_=0.f, o=0.f;
    float colr=0.f, colg=0.f, colb=0.f, rxr=-1.f, ryr=-1.f, pz=0.f;
    int pcam=0, pg=0;

    if (b < 8) {
        int idx = b*256 + tid;
        pcam = idx >> 10;
        pg   = idx & (NG - 1);
        int g = pg, cam = pcam;

        float qw = rot[g*4+0], qx = rot[g*4+1], qy = rot[g*4+2], qz = rot[g*4+3];
        float qn = rsqrtf(qw*qw + qx*qx + qy*qy + qz*qz);
        qw *= qn; qx *= qn; qy *= qn; qz *= qn;
        float r00 = 1.f - 2.f*(qy*qy + qz*qz), r01 = 2.f*(qx*qy - qw*qz), r02 = 2.f*(qx*qz + qw*qy);
        float r10 = 2.f*(qx*qy + qw*qz), r11 = 1.f - 2.f*(qx*qx + qz*qz), r12 = 2.f*(qy*qz - qw*qx);
        float r20 = 2.f*(qx*qz - qw*qy), r21 = 2.f*(qy*qz + qw*qx), r22 = 1.f - 2.f*(qx*qx + qy*qy);

        float sx = scale[g*3+0], sy = scale[g*3+1], sz = scale[g*3+2];
        float m00 = r00*sx, m01 = r01*sy, m02 = r02*sz;
        float m10 = r10*sx, m11 = r11*sy, m12 = r12*sz;
        float m20 = r20*sx, m21 = r21*sy, m22 = r22*sz;
        float c00 = m00*m00 + m01*m01 + m02*m02;
        float c01 = m00*m10 + m01*m11 + m02*m12;
        float c02 = m00*m20 + m01*m21 + m02*m22;
        float c11 = m10*m10 + m11*m11 + m12*m12;
        float c12 = m10*m20 + m11*m21 + m12*m22;
        float c22 = m20*m20 + m21*m21 + m22*m22;

        const float* vm = w2cs + cam*16;
        float R00 = vm[0],  R01 = vm[1],  R02 = vm[2],  t0 = vm[3];
        float R10 = vm[4],  R11 = vm[5],  R12 = vm[6],  t1 = vm[7];
        float R20 = vm[8],  R21 = vm[9],  R22 = vm[10], t2 = vm[11];

        float X = xyz[g*3], Y = xyz[g*3+1], Z = xyz[g*3+2];
        float px = R00*X + R01*Y + R02*Z + t0;
        float py = R10*X + R11*Y + R12*Z + t1;
        pz       = R20*X + R21*Y + R22*Z + t2;
        float rz = 1.f / pz;

        const float* Kc = Ks + cam*9;
        float fx = Kc[0], cx = Kc[2], fy = Kc[4], cy = Kc[5];
        float limx = 1.3f * (0.5f * (float)WW / fx);
        float limy = 1.3f * (0.5f * (float)HH / fy);
        float txc = pz * fminf(fmaxf(px*rz, -limx), limx);
        float tyc = pz * fminf(fmaxf(py*rz, -limy), limy);

        float v00 = R00*c00 + R01*c01 + R02*c02;
        float v01 = R00*c01 + R01*c11 + R02*c12;
        float v02 = R00*c02 + R01*c12 + R02*c22;
        float v10 = R10*c00 + R11*c01 + R12*c02;
        float v11 = R10*c01 + R11*c11 + R12*c12;
        float v12 = R10*c02 + R11*c12 + R12*c22;
        float v20 = R20*c00 + R21*c01 + R22*c02;
        float v21 = R20*c01 + R21*c11 + R22*c12;
        float v22 = R20*c02 + R21*c12 + R22*c22;
        float cc00 = v00*R00 + v01*R01 + v02*R02;
        float cc01 = v00*R10 + v01*R11 + v02*R12;
        float cc02 = v00*R20 + v01*R21 + v02*R22;
        float cc11 = v10*R10 + v11*R11 + v12*R12;
        float cc12 = v10*R20 + v11*R21 + v12*R22;
        float cc22 = v20*R20 + v21*R21 + v22*R22;

        float j00 = fx*rz, j02 = -fx*txc*rz*rz;
        float j11 = fy*rz, j12 = -fy*tyc*rz*rz;
        float a = j00*j00*cc00 + 2.f*j00*j02*cc02 + j02*j02*cc22 + EPS2D;
        float bq = j00*j11*cc01 + j00*j12*cc02 + j02*j11*cc12 + j02*j12*cc22;
        float d = j11*j11*cc11 + 2.f*j11*j12*cc12 + j12*j12*cc22 + EPS2D;
        float det = a*d - bq*bq;

        bool valid = (pz > 0.01f) && (pz < 100.f) && (det > 0.f);
        float idet = valid ? (1.f / det) : 0.f;
        ia  = d * idet;
        ib  = -bq * idet;
        id_ = a * idet;
        u = valid ? (fx*px*rz + cx) : 0.f;
        v = valid ? (fy*py*rz + cy) : 0.f;
        o = valid ? opac[g] : 0.f;
        colr = rgb[g*3+0]; colg = rgb[g*3+1]; colb = rgb[g*3+2];

        // Exact support: contributes iff sigma < tau = ln(255*o); ellipse
        // bbox half-extents sqrt(2*tau*a), sqrt(2*tau*d).
        float tau = __logf(255.f * o);
        if (valid && tau > 0.f) {
            rxr = sqrtf(2.f * tau * a) + 0.01f;
            ryr = sqrtf(2.f * tau * d) + 0.01f;
        }

        ws[Z_OFF + cam*NG + g] = pz;
    }

    grid_barrier(cnt + 0, NBLOCKS);

    if (b < 8) {
        // rank against the STORED z array (identical values for all threads
        // -> exact permutation; own stored pz round-trips bit-exactly)
        const float4* z4 = (const float4*)(ws + Z_OFF + pcam*NG);
        int rank = 0;
        #pragma unroll 8
        for (int j = 0; j < NG/4; j++) {
            float4 zz = z4[j];
            int j4 = j*4;
            rank += (zz.x < pz) || (zz.x == pz && (j4  ) < pg);
            rank += (zz.y < pz) || (zz.y == pz && (j4+1) < pg);
            rank += (zz.z < pz) || (zz.z == pz && (j4+2) < pg);
            rank += (zz.w < pz) || (zz.w == pz && (j4+3) < pg);
        }
        float4* dst = (float4*)(ws + B_OFF + (size_t)(pcam*NG + rank) * 12);
        dst[0] = make_float4(u, v, ia, ib);
        dst[1] = make_float4(id_, o, colr, colg);
        dst[2] = make_float4(colb, 0.f, 0.f, 0.f);

        unsigned int packed = 0xFFFFFFFFu;   // empty sentinel (tx0=255 never hits)
        if (rxr > 0.f) {
            int xmin = max((int)ceilf (u - rxr - 0.5f), 0);
            int xmax = min((int)floorf(u + rxr - 0.5f), WW-1);
            int ymin = max((int)ceilf (v - ryr - 0.5f), 0);
            int ymax = min((int)floorf(v + ryr - 0.5f), HH-1);
            if (xmin <= xmax && ymin <= ymax) {
                packed = (unsigned)(xmin>>3) | ((unsigned)(xmax>>3)<<8)
                       | ((unsigned)(ymin>>3)<<16) | ((unsigned)(ymax>>3)<<24);
            }
        }
        ((unsigned int*)(ws + BB_OFF))[pcam*NG + rank] = packed;
    }

    grid_barrier(cnt + 1, NBLOCKS);

    // ---- phase 3: render. 4 waves/block; wave s = depth segment s. ----
    const int TX = blockIdx.x, TY = blockIdx.y;
    const int lane = tid & 63;
    const int seg  = __builtin_amdgcn_readfirstlane(tid >> 6);

    __shared__ int    list[4][256];
    __shared__ float4 part[4][64];

    const float pxl = (float)(TX*8 + (lane & 7)) + 0.5f;
    const float pyl = (float)(TY*8 + (lane >> 3)) + 0.5f;

    for (int cam = 0; cam < NC; cam++) {
        const unsigned int* bbp = (const unsigned int*)(ws + BB_OFF) + cam*NG + seg*256;
        int nlist = 0;
        #pragma unroll
        for (int k = 0; k < 4; k++) {
            int gi = k*64 + lane;
            unsigned int pb = bbp[gi];
            int tx0 = pb & 255, tx1 = (pb>>8) & 255;
            int ty0 = (pb>>16) & 255, ty1 = (pb>>24) & 255;
            bool hit = (TX >= tx0) && (TX <= tx1) && (TY >= ty0) && (TY <= ty1);
            unsigned long long m = __ballot(hit);
            if (hit) {
                int pos = nlist + __popcll(m & ((1ull << lane) - 1ull));
                list[seg][pos] = seg*256 + gi;
            }
            nlist += __popcll(m);
        }

        const float* Bc = ws + B_OFF + (size_t)cam * NG * 12;
        float T = 1.f, cr = 0.f, cgc = 0.f, cb = 0.f;

        for (int ci = 0; ci < nlist; ci += 64) {
            int ent = list[seg][ci + lane];            // over-read safe (<=256)
            int cnt2 = min(64, nlist - ci);
            for (int j = 0; j < cnt2; j++) {
                int gid = __builtin_amdgcn_readlane(ent, j);   // wave-uniform
                const float* gp = Bc + gid * 12;               // -> s_load record
                float gu = gp[0], gv = gp[1], gia = gp[2], gib = gp[3];
                float gid_ = gp[4], go = gp[5], rr = gp[6], gg = gp[7], bv = gp[8];
                float dx = gu - pxl;
                float dy = gv - pyl;
                float sigma = 0.5f*(gia*dx*dx + gid_*dy*dy) + gib*dx*dy;
                float alpha = fminf(go * __expf(-sigma), ALPHA_MAX);
                alpha = (sigma >= 0.f && alpha > ALPHA_MIN) ? alpha : 0.f;
                float w = alpha * T;
                cr  += w * rr;
                cgc += w * gg;
                cb  += w * bv;
                T   -= alpha * T;
            }
            if (__all(T < 1e-4f)) break;   // this wave's segment transmittance
        }

        part[seg][lane] = make_float4(cr, cgc, cb, T);
        __syncthreads();

        if (tid < 64) {
            float4 c0 = part[0][lane];
            float Cr = c0.x, Cg = c0.y, Cb = c0.z, Tp = c0.w;
            #pragma unroll
            for (int s = 1; s < 4; s++) {
                float4 cs = part[s][lane];
                Cr += Tp * cs.x;
                Cg += Tp * cs.y;
                Cb += Tp * cs.z;
                Tp *= cs.w;
            }
            int p = (TY*8 + (lane >> 3)) * WW + TX*8 + (lane & 7);
            float* img = out + (size_t)cam * (HH*WW*3) + (size_t)p * 3;
            img[0] = Cr + Tp;           // bg = (1,1,1)
            img[1] = Cg + Tp;
            img[2] = Cb + Tp;
            out[(size_t)NC*HH*WW*3 + (size_t)cam*(HH*WW) + p] = 1.f - Tp;
        }
        __syncthreads();   // protect part[] reuse across cam iterations
    }
}

extern "C" void kernel_launch(void* const* d_in, const int* in_sizes, int n_in,
                              void* d_out, int out_size, void* d_ws, size_t ws_size,
                              hipStream_t stream) {
    const float* w2cs  = (const float*)d_in[0];
    const float* Ks    = (const float*)d_in[1];
    const float* xyz   = (const float*)d_in[2];
    const float* rgb   = (const float*)d_in[3];
    const float* opac  = (const float*)d_in[4];
    const float* scale = (const float*)d_in[5];
    const float* rot   = (const float*)d_in[6];
    float* out = (float*)d_out;
    float* ws  = (float*)d_ws;

    // zero the two barrier counters (ws is poisoned 0xAA before every launch)
    hipMemsetAsync((char*)d_ws + (size_t)CNT_OFF * sizeof(float), 0,
                   2 * sizeof(unsigned int), stream);
    fused_kernel<<<dim3(28, 28), 256, 0, stream>>>(w2cs, Ks, xyz, rgb, opac,
                                                   scale, rot, out, ws);
}

// Round 8
// 105.085 us; speedup vs baseline: 8.2292x; 8.2292x over previous
//
#include <hip/hip_runtime.h>
#include <math.h>

#define NG 1024
#define NC 2
#define HH 224
#define WW 224
#define TILES_X 28
#define TILES_Y 28
#define EPS2D 0.3f
#define ALPHA_MIN (1.0f/255.0f)
#define ALPHA_MAX 0.999f

// Workspace layout (float units):
//   B    at B_OFF : NC*NG*12 depth-sorted AoS (u,v,ia,ib | id,o,r,g | b,0,0,0)
//   bbox at BB_OFF: NC*NG packed uints (tile tx0|tx1<<8|ty0<<16|ty1<<24), sorted order
#define B_OFF  0
#define BB_OFF (B_OFF + NC*NG*12)

// Barrier-free prep+rank fusion: 8 blocks (4 per camera, 256 gaussians each).
// Each block REDUNDANTLY computes all 1024 z's of its camera into LDS
// (z = third row of the view transform, 3 FMAs per gaussian, xyz is L2-hit)
// -> __syncthreads -> full prep for own gaussians + exact O(N) rank against
// the LDS z array (bit-identical values: same expression, same compiled
// sequence) -> scatter record + packed tile-bbox to sorted position.
__global__ __launch_bounds__(256) void prep_rank_kernel(
        const float* __restrict__ w2cs, const float* __restrict__ Ks,
        const float* __restrict__ xyz, const float* __restrict__ rgb,
        const float* __restrict__ opac, const float* __restrict__ scale,
        const float* __restrict__ rot, float* __restrict__ ws) {
    const int blk = blockIdx.x;            // 0..7
    const int cam = blk >> 2;              // 4 blocks per camera
    const int g   = (blk & 3) * 256 + threadIdx.x;   // own gaussian, 0..1023

    __shared__ float zsh[NG];

    const float* vm = w2cs + cam*16;
    float R00 = vm[0],  R01 = vm[1],  R02 = vm[2],  t0 = vm[3];
    float R10 = vm[4],  R11 = vm[5],  R12 = vm[6],  t1 = vm[7];
    float R20 = vm[8],  R21 = vm[9],  R22 = vm[10], t2 = vm[11];

    // all 1024 z's of this camera (4 per thread)
    #pragma unroll
    for (int k = 0; k < 4; k++) {
        int gi = k*256 + threadIdx.x;
        float X = xyz[gi*3], Y = xyz[gi*3+1], Z = xyz[gi*3+2];
        zsh[gi] = R20*X + R21*Y + R22*Z + t2;
    }
    __syncthreads();

    // ---- full prep for own gaussian ----
    float qw = rot[g*4+0], qx = rot[g*4+1], qy = rot[g*4+2], qz = rot[g*4+3];
    float qn = rsqrtf(qw*qw + qx*qx + qy*qy + qz*qz);
    qw *= qn; qx *= qn; qy *= qn; qz *= qn;
    float r00 = 1.f - 2.f*(qy*qy + qz*qz), r01 = 2.f*(qx*qy - qw*qz), r02 = 2.f*(qx*qz + qw*qy);
    float r10 = 2.f*(qx*qy + qw*qz), r11 = 1.f - 2.f*(qx*qx + qz*qz), r12 = 2.f*(qy*qz - qw*qx);
    float r20 = 2.f*(qx*qz - qw*qy), r21 = 2.f*(qy*qz + qw*qx), r22 = 1.f - 2.f*(qx*qx + qy*qy);

    float sx = scale[g*3+0], sy = scale[g*3+1], sz = scale[g*3+2];
    float m00 = r00*sx, m01 = r01*sy, m02 = r02*sz;
    float m10 = r10*sx, m11 = r11*sy, m12 = r12*sz;
    float m20 = r20*sx, m21 = r21*sy, m22 = r22*sz;
    float c00 = m00*m00 + m01*m01 + m02*m02;
    float c01 = m00*m10 + m01*m11 + m02*m12;
    float c02 = m00*m20 + m01*m21 + m02*m22;
    float c11 = m10*m10 + m11*m11 + m12*m12;
    float c12 = m10*m20 + m11*m21 + m12*m22;
    float c22 = m20*m20 + m21*m21 + m22*m22;

    float X = xyz[g*3], Y = xyz[g*3+1], Z = xyz[g*3+2];
    float px = R00*X + R01*Y + R02*Z + t0;
    float py = R10*X + R11*Y + R12*Z + t1;
    float pz = zsh[g];                     // same bits as recompute
    float rz = 1.f / pz;

    const float* Kc = Ks + cam*9;
    float fx = Kc[0], cx = Kc[2], fy = Kc[4], cy = Kc[5];
    float limx = 1.3f * (0.5f * (float)WW / fx);
    float limy = 1.3f * (0.5f * (float)HH / fy);
    float txc = pz * fminf(fmaxf(px*rz, -limx), limx);
    float tyc = pz * fminf(fmaxf(py*rz, -limy), limy);

    float v00 = R00*c00 + R01*c01 + R02*c02;
    float v01 = R00*c01 + R01*c11 + R02*c12;
    float v02 = R00*c02 + R01*c12 + R02*c22;
    float v10 = R10*c00 + R11*c01 + R12*c02;
    float v11 = R10*c01 + R11*c11 + R12*c12;
    float v12 = R10*c02 + R11*c12 + R12*c22;
    float v20 = R20*c00 + R21*c01 + R22*c02;
    float v21 = R20*c01 + R21*c11 + R22*c12;
    float v22 = R20*c02 + R21*c12 + R22*c22;
    float cc00 = v00*R00 + v01*R01 + v02*R02;
    float cc01 = v00*R10 + v01*R11 + v02*R12;
    float cc02 = v00*R20 + v01*R21 + v02*R22;
    float cc11 = v10*R10 + v11*R11 + v12*R12;
    float cc12 = v10*R20 + v11*R21 + v12*R22;
    float cc22 = v20*R20 + v21*R21 + v22*R22;

    float j00 = fx*rz, j02 = -fx*txc*rz*rz;
    float j11 = fy*rz, j12 = -fy*tyc*rz*rz;
    float a = j00*j00*cc00 + 2.f*j00*j02*cc02 + j02*j02*cc22 + EPS2D;
    float bq = j00*j11*cc01 + j00*j12*cc02 + j02*j11*cc12 + j02*j12*cc22;
    float d = j11*j11*cc11 + 2.f*j11*j12*cc12 + j12*j12*cc22 + EPS2D;
    float det = a*d - bq*bq;

    bool valid = (pz > 0.01f) && (pz < 100.f) && (det > 0.f);
    float idet = valid ? (1.f / det) : 0.f;
    float ia  = d * idet;
    float ib  = -bq * idet;
    float id_ = a * idet;
    float u = valid ? (fx*px*rz + cx) : 0.f;
    float v = valid ? (fy*py*rz + cy) : 0.f;
    float o = valid ? opac[g] : 0.f;

    // ---- exact rank against the LDS z array (stable tie-break by index) ----
    float zi = pz;
    int rank = 0;
    const float4* z4 = (const float4*)zsh;
    #pragma unroll 8
    for (int j = 0; j < NG/4; j++) {
        float4 zz = z4[j];
        int j4 = j*4;
        rank += (zz.x < zi) || (zz.x == zi && (j4  ) < g);
        rank += (zz.y < zi) || (zz.y == zi && (j4+1) < g);
        rank += (zz.z < zi) || (zz.z == zi && (j4+2) < g);
        rank += (zz.w < zi) || (zz.w == zi && (j4+3) < g);
    }

    float4* dst = (float4*)(ws + B_OFF + (size_t)(cam*NG + rank) * 12);
    dst[0] = make_float4(u, v, ia, ib);
    dst[1] = make_float4(id_, o, rgb[g*3+0], rgb[g*3+1]);
    dst[2] = make_float4(rgb[g*3+2], 0.f, 0.f, 0.f);

    // Exact support bbox: contributes iff sigma < tau = ln(255*o); ellipse
    // bbox half-extents sqrt(2*tau*a), sqrt(2*tau*d) (a,d = cov2d diag).
    unsigned int packed = 0xFFFFFFFFu;   // empty sentinel (tx0=255 never hits)
    float tau = __logf(255.f * o);
    if (valid && tau > 0.f) {
        float rx = sqrtf(2.f * tau * a) + 0.01f;
        float ry = sqrtf(2.f * tau * d) + 0.01f;
        int xmin = max((int)ceilf (u - rx - 0.5f), 0);
        int xmax = min((int)floorf(u + rx - 0.5f), WW-1);
        int ymin = max((int)ceilf (v - ry - 0.5f), 0);
        int ymax = min((int)floorf(v + ry - 0.5f), HH-1);
        if (xmin <= xmax && ymin <= ymax) {
            packed = (unsigned)(xmin>>3) | ((unsigned)(xmax>>3)<<8)
                   | ((unsigned)(ymin>>3)<<16) | ((unsigned)(ymax>>3)<<24);
        }
    }
    ((unsigned int*)(ws + BB_OFF))[cam*NG + rank] = packed;
}

// Block = 256 threads = 4 waves per 8x8 tile. Wave s ballot-compacts and
// composites depth-segment s (256 sorted gaussians) filtered to this tile;
// list entries broadcast via v_readlane; partials merged per pixel via the
// associative compositing law (C,T)+(C',T') = (C + T*C', T*T').
__global__ __launch_bounds__(256) void render_kernel(const float* __restrict__ ws,
                                                     float* __restrict__ out) {
    const int cam  = blockIdx.z;
    const int TX = blockIdx.x, TY = blockIdx.y;
    const int lane = threadIdx.x & 63;
    const int seg  = __builtin_amdgcn_readfirstlane(threadIdx.x >> 6);

    __shared__ int    list[4][256];
    __shared__ float4 part[4][64];

    const unsigned int* bb = (const unsigned int*)(ws + BB_OFF) + cam*NG + seg*256;
    int nlist = 0;
    #pragma unroll
    for (int k = 0; k < 4; k++) {
        int gi = k*64 + lane;
        unsigned int pb = bb[gi];
        int tx0 = pb & 255, tx1 = (pb>>8) & 255;
        int ty0 = (pb>>16) & 255, ty1 = (pb>>24) & 255;
        bool hit = (TX >= tx0) && (TX <= tx1) && (TY >= ty0) && (TY <= ty1);
        unsigned long long m = __ballot(hit);
        if (hit) {
            int pos = nlist + __popcll(m & ((1ull << lane) - 1ull));
            list[seg][pos] = seg*256 + gi;
        }
        nlist += __popcll(m);
    }

    const float* Bc = ws + B_OFF + (size_t)cam * NG * 12;
    const float pxl = (float)(TX*8 + (lane & 7)) + 0.5f;
    const float pyl = (float)(TY*8 + (lane >> 3)) + 0.5f;

    float T = 1.f, cr = 0.f, cg = 0.f, cb = 0.f;

    for (int ci = 0; ci < nlist; ci += 64) {
        int ent = list[seg][ci + lane];            // <=256 bound, safe over-read
        int cnt = min(64, nlist - ci);
        for (int j = 0; j < cnt; j++) {
            int gid = __builtin_amdgcn_readlane(ent, j);   // wave-uniform
            const float* gp = Bc + gid * 12;               // -> s_load record
            float u  = gp[0], v  = gp[1], ia = gp[2], ib = gp[3];
            float id = gp[4], o  = gp[5], rr = gp[6], gg = gp[7], bv = gp[8];
            float dx = u - pxl;
            float dy = v - pyl;
            float sigma = 0.5f*(ia*dx*dx + id*dy*dy) + ib*dx*dy;
            float alpha = fminf(o * __expf(-sigma), ALPHA_MAX);
            alpha = (sigma >= 0.f && alpha > ALPHA_MIN) ? alpha : 0.f;
            float w = alpha * T;
            cr += w * rr;
            cg += w * gg;
            cb += w * bv;
            T  -= alpha * T;
        }
        if (__all(T < 1e-4f)) break;   // this wave's segment transmittance
    }

    part[seg][lane] = make_float4(cr, cg, cb, T);
    __syncthreads();

    if (threadIdx.x < 64) {
        float4 c0 = part[0][lane];
        float Cr = c0.x, Cg = c0.y, Cb = c0.z, Tp = c0.w;
        #pragma unroll
        for (int s = 1; s < 4; s++) {
            float4 cs = part[s][lane];
            Cr += Tp * cs.x;
            Cg += Tp * cs.y;
            Cb += Tp * cs.z;
            Tp *= cs.w;
        }
        int p = (TY*8 + (lane >> 3)) * WW + TX*8 + (lane & 7);
        float* img = out + (size_t)cam * (HH*WW*3) + (size_t)p * 3;
        img[0] = Cr + Tp;           // bg = (1,1,1)
        img[1] = Cg + Tp;
        img[2] = Cb + Tp;
        out[(size_t)NC*HH*WW*3 + (size_t)cam*(HH*WW) + p] = 1.f - Tp;
    }
}

extern "C" void kernel_launch(void* const* d_in, const int* in_sizes, int n_in,
                              void* d_out, int out_size, void* d_ws, size_t ws_size,
                              hipStream_t stream) {
    const float* w2cs  = (const float*)d_in[0];
    const float* Ks    = (const float*)d_in[1];
    const float* xyz   = (const float*)d_in[2];
    const float* rgb   = (const float*)d_in[3];
    const float* opac  = (const float*)d_in[4];
    const float* scale = (const float*)d_in[5];
    const float* rot   = (const float*)d_in[6];
    float* out = (float*)d_out;
    float* ws  = (float*)d_ws;

    prep_rank_kernel<<<dim3(8), 256, 0, stream>>>(w2cs, Ks, xyz, rgb, opac, scale, rot, ws);
    render_kernel<<<dim3(TILES_X, TILES_Y, NC), 256, 0, stream>>>(ws, out);
}

// Round 9
// 80.997 us; speedup vs baseline: 10.6766x; 1.2974x over previous
//
#include <hip/hip_runtime.h>
#include <math.h>

#define NG 1024
#define NC 2
#define HH 224
#define WW 224
#define TILES_X 28
#define TILES_Y 28
#define EPS2D 0.3f
#define ALPHA_MIN (1.0f/255.0f)
#define ALPHA_MAX 0.999f
#define MAXL 512   // per-tile list capacity (measured est. worst ~250 incl. superset inflation)

// Single dispatch, zero cross-block deps. Per 8x8-pixel tile block:
//  1) conservative prefilter of all 1024 gaussians (superset of exact support:
//     lambda_max(Sigma3d) <= s_max^2 and |j02| <= fx*lim*rz bound the conic
//     diagonal; extra gaussians contribute exactly 0 via the alpha>1/255 test)
//  2) compact (z_bits<<10)|gid keys into LDS (shared-atomic slots; keys carry
//     the full (z, gid) stable order, so slot order is irrelevant)
//  3) in-block bitonic sort of the keys — per-tile (z,gid) order == global
//     stable sort restricted to the tile
//  4) full prep only for listed gaussians, written straight to sorted slots
//  5) 4 depth-segment waves composite + associative merge (C,T) algebra.
__global__ __launch_bounds__(256) void fused_kernel(
        const float* __restrict__ w2cs, const float* __restrict__ Ks,
        const float* __restrict__ xyz, const float* __restrict__ rgb,
        const float* __restrict__ opac, const float* __restrict__ scale,
        const float* __restrict__ rot, float* __restrict__ out) {
    const int cam = blockIdx.z;
    const int TX = blockIdx.x, TY = blockIdx.y;
    const int tid = threadIdx.x;
    const int lane = tid & 63;
    const int wv   = tid >> 6;

    __shared__ unsigned long long keys[MAXL];
    __shared__ float4 sA[MAXL];          // u, v, ia, ib
    __shared__ float4 sB[MAXL];          // id, o, r, g
    __shared__ float  sC[MAXL];          // b
    __shared__ float4 part[4][64];
    __shared__ int scnt;

    if (tid == 0) scnt = 0;
    __syncthreads();

    const float* vm = w2cs + cam*16;
    const float R00 = vm[0],  R01 = vm[1],  R02 = vm[2],  t0 = vm[3];
    const float R10 = vm[4],  R11 = vm[5],  R12 = vm[6],  t1 = vm[7];
    const float R20 = vm[8],  R21 = vm[9],  R22 = vm[10], t2 = vm[11];
    const float* Kc = Ks + cam*9;
    const float fx = Kc[0], cx = Kc[2], fy = Kc[4], cy = Kc[5];
    const float limx = 1.3f * (0.5f * (float)WW / fx);
    const float limy = 1.3f * (0.5f * (float)HH / fy);

    // ---- phase 1: conservative prefilter, 4 gaussians per thread ----
    #pragma unroll
    for (int k = 0; k < 4; k++) {
        int g = k*256 + tid;
        float X = xyz[g*3], Y = xyz[g*3+1], Z = xyz[g*3+2];
        float pz = R20*X + R21*Y + R22*Z + t2;
        float o  = opac[g];
        float tau = __logf(255.f * o);
        bool cand = (pz > 0.01f) && (pz < 100.f) && (tau > 0.f);
        if (cand) {
            float rz = 1.f / pz;
            float px = R00*X + R01*Y + R02*Z + t0;
            float py = R10*X + R11*Y + R12*Z + t1;
            float u = fx*px*rz + cx;
            float v = fy*py*rz + cy;
            float sx = scale[g*3+0], sy = scale[g*3+1], sz = scale[g*3+2];
            float smax = fmaxf(sx, fmaxf(sy, sz));
            float j00 = fx*rz, j11 = fy*rz;
            float j02m = fx*limx*rz, j12m = fy*limy*rz;   // |j02| bound via |tx|<=limx*z
            float abnd = smax*smax*(j00*j00 + j02m*j02m) + EPS2D;  // >= exact a
            float dbnd = smax*smax*(j11*j11 + j12m*j12m) + EPS2D;  // >= exact d
            float rx = sqrtf(2.f*tau*abnd) + 0.01f;
            float ry = sqrtf(2.f*tau*dbnd) + 0.01f;
            int xmin = max((int)ceilf (u - rx - 0.5f), 0);
            int xmax = min((int)floorf(u + rx - 0.5f), WW-1);
            int ymin = max((int)ceilf (v - ry - 0.5f), 0);
            int ymax = min((int)floorf(v + ry - 0.5f), HH-1);
            cand = (xmin <= xmax) && (ymin <= ymax) &&
                   (TX >= (xmin>>3)) && (TX <= (xmax>>3)) &&
                   (TY >= (ymin>>3)) && (TY <= (ymax>>3));
            if (cand) {
                // reserve slots wave-cooperatively (order irrelevant; key = order)
                unsigned long long m = __ballot(true);
                // NOTE: all lanes with cand==true are in m via the ballot below
                (void)m;
            }
        }
        unsigned long long m = __ballot(cand);
        int cw = __popcll(m);
        if (cw) {
            int basepos = 0;
            if (lane == 0) basepos = atomicAdd(&scnt, cw);
            basepos = __shfl(basepos, 0);
            if (cand) {
                float zz = R20*X + R21*Y + R22*Z + t2;  // same expr -> same bits
                int pos = basepos + __popcll(m & ((1ull << lane) - 1ull));
                if (pos < MAXL)
                    keys[pos] = ((unsigned long long)__float_as_uint(zz) << 10)
                              | (unsigned long long)g;
            }
        }
    }
    __syncthreads();
    int n = min(scnt, MAXL);

    // ---- phase 2: bitonic sort of keys (ascending (z_bits, gid)) ----
    int P = 2; while (P < n) P <<= 1;
    for (int i = tid; i < P; i += 256) if (i >= n) keys[i] = ~0ull;
    __syncthreads();
    for (int kk = 2; kk <= P; kk <<= 1) {
        for (int j = kk >> 1; j > 0; j >>= 1) {
            for (int i0 = tid; i0 < P; i0 += 256) {
                int ixj = i0 ^ j;
                if (ixj > i0) {
                    unsigned long long a = keys[i0], b = keys[ixj];
                    bool up = ((i0 & kk) == 0);
                    if ((a > b) == up) { keys[i0] = b; keys[ixj] = a; }
                }
            }
            __syncthreads();
        }
    }

    // ---- phase 3: full prep for listed gaussians, into sorted slots ----
    for (int i = tid; i < n; i += 256) {
        int g = (int)(keys[i] & 1023ull);

        float qw = rot[g*4+0], qx = rot[g*4+1], qy = rot[g*4+2], qz = rot[g*4+3];
        float qn = rsqrtf(qw*qw + qx*qx + qy*qy + qz*qz);
        qw *= qn; qx *= qn; qy *= qn; qz *= qn;
        float r00 = 1.f - 2.f*(qy*qy + qz*qz), r01 = 2.f*(qx*qy - qw*qz), r02 = 2.f*(qx*qz + qw*qy);
        float r10 = 2.f*(qx*qy + qw*qz), r11 = 1.f - 2.f*(qx*qx + qz*qz), r12 = 2.f*(qy*qz - qw*qx);
        float r20 = 2.f*(qx*qz - qw*qy), r21 = 2.f*(qy*qz + qw*qx), r22 = 1.f - 2.f*(qx*qx + qy*qy);

        float sx = scale[g*3+0], sy = scale[g*3+1], sz = scale[g*3+2];
        float m00 = r00*sx, m01 = r01*sy, m02 = r02*sz;
        float m10 = r10*sx, m11 = r11*sy, m12 = r12*sz;
        float m20 = r20*sx, m21 = r21*sy, m22 = r22*sz;
        float c00 = m00*m00 + m01*m01 + m02*m02;
        float c01 = m00*m10 + m01*m11 + m02*m12;
        float c02 = m00*m20 + m01*m21 + m02*m22;
        float c11 = m10*m10 + m11*m11 + m12*m12;
        float c12 = m10*m20 + m11*m21 + m12*m22;
        float c22 = m20*m20 + m21*m21 + m22*m22;

        float X = xyz[g*3], Y = xyz[g*3+1], Z = xyz[g*3+2];
        float px = R00*X + R01*Y + R02*Z + t0;
        float py = R10*X + R11*Y + R12*Z + t1;
        float pz = R20*X + R21*Y + R22*Z + t2;
        float rz = 1.f / pz;

        float txc = pz * fminf(fmaxf(px*rz, -limx), limx);
        float tyc = pz * fminf(fmaxf(py*rz, -limy), limy);

        float v00 = R00*c00 + R01*c01 + R02*c02;
        float v01 = R00*c01 + R01*c11 + R02*c12;
        float v02 = R00*c02 + R01*c12 + R02*c22;
        float v10 = R10*c00 + R11*c01 + R12*c02;
        float v11 = R10*c01 + R11*c11 + R12*c12;
        float v12 = R10*c02 + R11*c12 + R12*c22;
        float v20 = R20*c00 + R21*c01 + R22*c02;
        float v21 = R20*c01 + R21*c11 + R22*c12;
        float v22 = R20*c02 + R21*c12 + R22*c22;
        float cc00 = v00*R00 + v01*R01 + v02*R02;
        float cc01 = v00*R10 + v01*R11 + v02*R12;
        float cc02 = v00*R20 + v01*R21 + v02*R22;
        float cc11 = v10*R10 + v11*R11 + v12*R12;
        float cc12 = v10*R20 + v11*R21 + v12*R22;
        float cc22 = v20*R20 + v21*R21 + v22*R22;

        float j00 = fx*rz, j02 = -fx*txc*rz*rz;
        float j11 = fy*rz, j12 = -fy*tyc*rz*rz;
        float a = j00*j00*cc00 + 2.f*j00*j02*cc02 + j02*j02*cc22 + EPS2D;
        float bq = j00*j11*cc01 + j00*j12*cc02 + j02*j11*cc12 + j02*j12*cc22;
        float d = j11*j11*cc11 + 2.f*j11*j12*cc12 + j12*j12*cc22 + EPS2D;
        float det = a*d - bq*bq;

        bool valid = (pz > 0.01f) && (pz < 100.f) && (det > 0.f);
        float idet = valid ? (1.f / det) : 0.f;
        float ia  = d * idet;
        float ib  = -bq * idet;
        float id_ = a * idet;
        float u = valid ? (fx*px*rz + cx) : 0.f;
        float v = valid ? (fy*py*rz + cy) : 0.f;
        float o = valid ? opac[g] : 0.f;

        sA[i] = make_float4(u, v, ia, ib);
        sB[i] = make_float4(id_, o, rgb[g*3+0], rgb[g*3+1]);
        sC[i] = rgb[g*3+2];
    }
    __syncthreads();

    // ---- phase 4: segmented composite (wave wv = depth segment wv) ----
    const float pxl = (float)(TX*8 + (lane & 7)) + 0.5f;
    const float pyl = (float)(TY*8 + (lane >> 3)) + 0.5f;
    int seglen = (n + 3) >> 2;
    int js = wv * seglen;
    int je = min(n, js + seglen);

    float T = 1.f, cr = 0.f, cg = 0.f, cb = 0.f;
    for (int j = js; j < je; j++) {
        float4 ga = sA[j];        // wave-uniform addr -> LDS broadcast
        float4 gb = sB[j];
        float  bv = sC[j];
        float dx = ga.x - pxl;
        float dy = ga.y - pyl;
        float sigma = 0.5f*(ga.z*dx*dx + gb.x*dy*dy) + ga.w*dx*dy;
        float alpha = fminf(gb.y * __expf(-sigma), ALPHA_MAX);
        alpha = (sigma >= 0.f && alpha > ALPHA_MIN) ? alpha : 0.f;
        float w = alpha * T;
        cr += w * gb.z;
        cg += w * gb.w;
        cb += w * bv;
        T  -= alpha * T;
        if (((j - js) & 15) == 15 && __all(T < 1e-4f)) break;
    }

    part[wv][lane] = make_float4(cr, cg, cb, T);
    __syncthreads();

    if (tid < 64) {
        float4 c0 = part[0][lane];
        float Cr = c0.x, Cg = c0.y, Cb = c0.z, Tp = c0.w;
        #pragma unroll
        for (int s = 1; s < 4; s++) {
            float4 cs = part[s][lane];
            Cr += Tp * cs.x;
            Cg += Tp * cs.y;
            Cb += Tp * cs.z;
            Tp *= cs.w;
        }
        int p = (TY*8 + (lane >> 3)) * WW + TX*8 + (lane & 7);
        float* img = out + (size_t)cam * (HH*WW*3) + (size_t)p * 3;
        img[0] = Cr + Tp;           // bg = (1,1,1)
        img[1] = Cg + Tp;
        img[2] = Cb + Tp;
        out[(size_t)NC*HH*WW*3 + (size_t)cam*(HH*WW) + p] = 1.f - Tp;
    }
}

extern "C" void kernel_launch(void* const* d_in, const int* in_sizes, int n_in,
                              void* d_out, int out_size, void* d_ws, size_t ws_size,
                              hipStream_t stream) {
    const float* w2cs  = (const float*)d_in[0];
    const float* Ks    = (const float*)d_in[1];
    const float* xyz   = (const float*)d_in[2];
    const float* rgb   = (const float*)d_in[3];
    const float* opac  = (const float*)d_in[4];
    const float* scale = (const float*)d_in[5];
    const float* rot   = (const float*)d_in[6];
    float* out = (float*)d_out;

    fused_kernel<<<dim3(TILES_X, TILES_Y, NC), 256, 0, stream>>>(
        w2cs, Ks, xyz, rgb, opac, scale, rot, out);
}